// Round 1
// baseline (392.282 us; speedup 1.0000x reference)
//
#include <hip/hip_runtime.h>
#include <math.h>

#define NEG -1e30f

__device__ __forceinline__ float logaddexpf_(float x, float y) {
    float m = fmaxf(x, y);
    return m + logf(expf(x - m) + expf(y - m));
}

// Stage 1: per (b,t,u) row of V=1024 logits, compute lse and emit
//   blank_lp[row] = logits[row,0]   - lse
//   y_lp[b,t,u]   = logits[row,tgt] - lse   (u < U)
// One wave (64 lanes) per row, 16 floats/lane as 4x float4.
__global__ __launch_bounds__(256) void lse_kernel(
    const float* __restrict__ logits,
    const int* __restrict__ targets,
    float* __restrict__ blank_lp,
    float* __restrict__ y_lp,
    int B, int T, int U, int V) {
    const int wave = threadIdx.x >> 6;
    const int lane = threadIdx.x & 63;
    const long long row = (long long)blockIdx.x * 4 + wave;
    const long long nrows = (long long)B * T * (U + 1);
    if (row >= nrows) return;
    const float* base = logits + row * (long long)V;

    float4 d[4];
    float vmax = -INFINITY;
#pragma unroll
    for (int c = 0; c < 4; ++c) {
        d[c] = reinterpret_cast<const float4*>(base)[c * 64 + lane];
        vmax = fmaxf(vmax, fmaxf(fmaxf(d[c].x, d[c].y), fmaxf(d[c].z, d[c].w)));
    }
#pragma unroll
    for (int off = 32; off; off >>= 1) vmax = fmaxf(vmax, __shfl_xor(vmax, off, 64));
    float s = 0.f;
#pragma unroll
    for (int c = 0; c < 4; ++c) {
        s += expf(d[c].x - vmax) + expf(d[c].y - vmax) +
             expf(d[c].z - vmax) + expf(d[c].w - vmax);
    }
#pragma unroll
    for (int off = 32; off; off >>= 1) s += __shfl_xor(s, off, 64);

    if (lane == 0) {
        const float lse = vmax + logf(s);
        const int u = (int)(row % (U + 1));
        const long long bt = row / (U + 1);          // b*T + t
        blank_lp[row] = base[0] - lse;
        if (u < U) {
            const int b = (int)(bt / T);
            const long long t = bt % T;
            const int tgt = targets[b * U + u];
            y_lp[((long long)b * T + t) * U + u] = base[tgt] - lse;
        }
    }
}

// Stage 2: alpha recursion. One wave per batch element. Lane l owns u = l+1;
// alpha[u=0] kept redundantly in all lanes. Per time step:
//   a[u]   = alpha[u] + blank[t-1,u]
//   c[u]   = exclusive cumsum_u of y[t,:]   (inclusive add-scan over lanes)
//   z[u]   = logcumsumexp(a - c)            (inclusive logaddexp-scan, seeded with a0)
//   alpha' = c + z  (masked to NEG for u > L)
__global__ __launch_bounds__(512) void alpha_kernel(
    const float* __restrict__ blank_lp,
    const float* __restrict__ y_lp,
    const int* __restrict__ in_len,
    const int* __restrict__ tgt_len,
    float* __restrict__ out,
    int B, int T, int U) {
    __shared__ float partial[8];
    const int wave = threadIdx.x >> 6;
    const int lane = threadIdx.x & 63;
    const int b = wave;

    if (b < B) {
        const int Tb = in_len[b];
        const int L  = tgt_len[b];
        const float* yb = y_lp + (long long)b * T * U;
        const float* bb = blank_lp + (long long)b * T * (U + 1);

        // t = 0 init: alpha[u] = sum_{k<u} y[0,k]
        float yv = yb[lane];
        float c = (lane < L) ? yv : 0.f;
#pragma unroll
        for (int off = 1; off < 64; off <<= 1) {
            float o = __shfl_up(c, off, 64);
            if (lane >= off) c += o;
        }
        float alpha_u = (lane + 1 <= L) ? c : NEG;
        float alpha0 = 0.f;

        for (int t = 1; t < Tb; ++t) {
            const float* brow = bb + (long long)(t - 1) * (U + 1);
            const float bp0 = brow[0];
            const float bpu = brow[lane + 1];
            const float a0 = alpha0 + bp0;
            const float au = alpha_u + bpu;

            float yv2 = yb[(long long)t * U + lane];
            float cc = (lane < L) ? yv2 : 0.f;
#pragma unroll
            for (int off = 1; off < 64; off <<= 1) {
                float o = __shfl_up(cc, off, 64);
                if (lane >= off) cc += o;
            }

            float d = au - cc;
            if (lane + 1 > L) d = NEG;
            float z = d;
#pragma unroll
            for (int off = 1; off < 64; off <<= 1) {
                float o = __shfl_up(z, off, 64);
                if (lane >= off) z = logaddexpf_(z, o);
            }
            z = logaddexpf_(z, a0);

            alpha_u = (lane + 1 <= L) ? (cc + z) : NEG;
            alpha0 = a0;
        }

        const float aL = __shfl(alpha_u, L - 1, 64);
        const float bfin = bb[(long long)(Tb - 1) * (U + 1) + L];
        if (lane == 0) partial[wave] = aL + bfin;
    }
    __syncthreads();
    if (threadIdx.x == 0) {
        float s = 0.f;
        for (int w = 0; w < B; ++w) s += partial[w];
        out[0] = -s / (float)B;
    }
}

extern "C" void kernel_launch(void* const* d_in, const int* in_sizes, int n_in,
                              void* d_out, int out_size, void* d_ws, size_t ws_size,
                              hipStream_t stream) {
    const float* logits  = (const float*)d_in[0];
    const int* targets   = (const int*)d_in[1];
    const int* in_len    = (const int*)d_in[2];
    const int* tgt_len   = (const int*)d_in[3];

    const int B = in_sizes[2];
    const int U = in_sizes[1] / B;
    const int V = 1024;
    const int T = (int)((long long)in_sizes[0] / ((long long)B * (U + 1) * V));

    float* blank_lp = (float*)d_ws;
    float* y_lp = blank_lp + (long long)B * T * (U + 1);

    const long long rows = (long long)B * T * (U + 1);
    const int blocks = (int)((rows + 3) / 4);

    hipLaunchKernelGGL(lse_kernel, dim3(blocks), dim3(256), 0, stream,
                       logits, targets, blank_lp, y_lp, B, T, U, V);
    hipLaunchKernelGGL(alpha_kernel, dim3(1), dim3(512), 0, stream,
                       blank_lp, y_lp, in_len, tgt_len, (float*)d_out, B, T, U);
}

// Round 2
// 214.591 us; speedup vs baseline: 1.8281x; 1.8281x over previous
//
#include <hip/hip_runtime.h>
#include <math.h>

#define NEG -1e30f

__device__ __forceinline__ float lae(float x, float y) {
    float m = fmaxf(x, y);
    float dm = fminf(x, y) - m;
    return m + __logf(1.f + __expf(dm));
}

// Stage 1: per (b,t,u) row of V=1024 logits, compute lse and emit
//   blank_d[b][t+u][u] = logits[row,0]   - lse     (diag layout, pitch U+1)
//   y_d[b][t+u][u]     = logits[row,tgt] - lse     (diag layout, pitch U, u<U)
// One wave (64 lanes) per row, 16 floats/lane as 4x float4. Memory-bound.
__global__ __launch_bounds__(256) void lse_kernel(
    const float* __restrict__ logits,
    const int* __restrict__ targets,
    float* __restrict__ blank_d,
    float* __restrict__ y_d,
    int B, int T, int U, int V) {
    const int wave = threadIdx.x >> 6;
    const int lane = threadIdx.x & 63;
    const long long row = (long long)blockIdx.x * 4 + wave;
    const long long nrows = (long long)B * T * (U + 1);
    if (row >= nrows) return;
    const float* base = logits + row * (long long)V;

    float4 d4[4];
    float vmax = -INFINITY;
#pragma unroll
    for (int c = 0; c < 4; ++c) {
        d4[c] = reinterpret_cast<const float4*>(base)[c * 64 + lane];
        vmax = fmaxf(vmax, fmaxf(fmaxf(d4[c].x, d4[c].y), fmaxf(d4[c].z, d4[c].w)));
    }
#pragma unroll
    for (int off = 32; off; off >>= 1) vmax = fmaxf(vmax, __shfl_xor(vmax, off, 64));
    float s = 0.f;
#pragma unroll
    for (int c = 0; c < 4; ++c) {
        s += __expf(d4[c].x - vmax) + __expf(d4[c].y - vmax) +
             __expf(d4[c].z - vmax) + __expf(d4[c].w - vmax);
    }
#pragma unroll
    for (int off = 32; off; off >>= 1) s += __shfl_xor(s, off, 64);

    if (lane == 0) {
        const float lse = vmax + __logf(s);
        const int U1 = U + 1;
        const int D = T + U;
        const int u = (int)(row % U1);
        const long long bt = row / U1;              // b*T + t
        const int b = (int)(bt / T);
        const int t = (int)(bt % T);
        blank_d[((long long)b * D + (t + u)) * U1 + u] = base[0] - lse;
        if (u < U) {
            const int tgt = targets[b * U + u];
            y_d[((long long)b * D + (t + u)) * U + u] = base[tgt] - lse;
        }
    }
}

// Stage 2: anti-diagonal wavefront. One wave per batch element; lane l owns
// u = l; lane 63 additionally tracks u = 64 (uses its own prev value as the
// left neighbor). Per diagonal d: one shfl_up + one logaddexp per cell.
//   alpha[t,u] = lae(alpha[t-1,u] + blank[t-1,u], alpha[t,u-1] + y[t,u-1])
// with t = d - u; operand rows live at diag index d-1 in the diag layout,
// so loads are row-base (scalar) + lane offset -> coalesced. Depth-2
// register prefetch hides L2 latency. Lanes with invalid t hold NEG-ish
// finite junk that never feeds a valid cell (y masked at u-1 >= L).
__global__ __launch_bounds__(512) void alpha_diag_kernel(
    const float* __restrict__ blank_d,
    const float* __restrict__ y_d,
    const int* __restrict__ in_len,
    const int* __restrict__ tgt_len,
    float* __restrict__ out,
    int B, int T, int U) {
    __shared__ float partial[16];
    const int wave = threadIdx.x >> 6;
    const int lane = threadIdx.x & 63;
    const int D = T + U;
    const int P1 = U + 1;

    if (wave < B) {
        const int b = wave;
        const int Tb = in_len[b];
        const int L = tgt_len[b];
        const float* bd = blank_d + (long long)b * D * P1;
        const float* yd = y_d + (long long)b * D * U;
        const int dstar = Tb - 1 + L;

        float val = (lane == 0) ? 0.f : NEG;
        float v64 = NEG;
        const int ym = (lane > 0) ? (lane - 1) : 0;   // y col (clamped for lane 0)
        const bool t2ok = (lane >= 1) && (lane - 1 < L);
        const bool t2ok64 = (U - 1 < L);              // u=64 path uses y col 63

        // preload rows for d=1 (A) and d=2 (B)
        int rA = 0;
        int rB = (1 < D - 1) ? 1 : D - 1;
        float bvA = bd[rA * P1 + lane];
        float yvA = yd[rA * U + ym];
        float b64A = bd[rA * P1 + U];
        float y63A = yd[rA * U + (U - 1)];
        float bvB = bd[rB * P1 + lane];
        float yvB = yd[rB * U + ym];
        float b64B = bd[rB * P1 + U];
        float y63B = yd[rB * U + (U - 1)];

        for (int d = 1; d <= dstar; ++d) {
            const float pv = val;
            const float ps = __shfl_up(pv, 1, 64);
            const float t1 = pv + bvA;
            const float t2 = t2ok ? (ps + yvA) : NEG;
            val = lae(t1, t2);
            // u = 64 cell (only meaningful on lane 63, only used when L == U)
            const float t164 = v64 + b64A;
            const float t264 = t2ok64 ? (pv + y63A) : NEG;
            v64 = lae(t164, t264);
            // rotate buffers, prefetch row for diag d+2
            bvA = bvB; yvA = yvB; b64A = b64B; y63A = y63B;
            int r = d + 1;
            if (r > D - 1) r = D - 1;
            bvB = bd[r * P1 + lane];
            yvB = yd[r * U + ym];
            b64B = bd[r * P1 + U];
            y63B = yd[r * U + (U - 1)];
        }

        const float aL = (L <= 63) ? __shfl(val, L, 64) : __shfl(v64, 63, 64);
        const float bfin = bd[(long long)dstar * P1 + L];
        if (lane == 0) partial[wave] = aL + bfin;
    }
    __syncthreads();
    if (threadIdx.x == 0) {
        float s = 0.f;
        for (int w = 0; w < B; ++w) s += partial[w];
        out[0] = -s / (float)B;
    }
}

extern "C" void kernel_launch(void* const* d_in, const int* in_sizes, int n_in,
                              void* d_out, int out_size, void* d_ws, size_t ws_size,
                              hipStream_t stream) {
    const float* logits  = (const float*)d_in[0];
    const int* targets   = (const int*)d_in[1];
    const int* in_len    = (const int*)d_in[2];
    const int* tgt_len   = (const int*)d_in[3];

    const int B = in_sizes[2];
    const int U = in_sizes[1] / B;
    const int V = 1024;
    const int T = (int)((long long)in_sizes[0] / ((long long)B * (U + 1) * V));
    const int D = T + U;

    float* blank_d = (float*)d_ws;
    float* y_d = blank_d + (long long)B * D * (U + 1);

    const long long rows = (long long)B * T * (U + 1);
    const int blocks = (int)((rows + 3) / 4);

    hipLaunchKernelGGL(lse_kernel, dim3(blocks), dim3(256), 0, stream,
                       logits, targets, blank_d, y_d, B, T, U, V);
    hipLaunchKernelGGL(alpha_diag_kernel, dim3(1), dim3(512), 0, stream,
                       blank_d, y_d, in_len, tgt_len, (float*)d_out, B, T, U);
}

// Round 3
// 139.124 us; speedup vs baseline: 2.8197x; 1.5424x over previous
//
#include <hip/hip_runtime.h>
#include <math.h>

#define NEG -1e30f
#define LOG2E 1.4426950408889634f
#define LN2 0.6931471805599453f

// lane i <- lane i-1 (shfl_up by 1) via DPP wave_shr1 (0x138). VALU-latency,
// no LDS round-trip. Lane 0 keeps `old` (0) -- its consumer is masked.
__device__ __forceinline__ float shup1(float x) {
    return __int_as_float(
        __builtin_amdgcn_update_dpp(0, __float_as_int(x), 0x138, 0xF, 0xF, false));
}

// base-2 logaddexp: log2(2^x + 2^y). v_exp_f32/v_log_f32 are natively base-2.
__device__ __forceinline__ float lae2(float x, float y) {
    float m = fmaxf(x, y);
    float dm = fminf(x, y) - m;
    return m + __builtin_amdgcn_logf(1.f + __builtin_amdgcn_exp2f(dm));
}

// Stage 1: per (b,t,u) row of V=1024 logits, compute lse and emit (base-2!)
//   blank_d[b][t+u][u] = (logits[row,0]   - lse) * log2e   (pitch U+1)
//   y_d[b][t+u][u]     = (logits[row,tgt] - lse) * log2e   (pitch U, u<U)
// One wave per row, 16 floats/lane as 4x float4. Memory-bound (545 MB read).
__global__ __launch_bounds__(256) void lse_kernel(
    const float* __restrict__ logits,
    const int* __restrict__ targets,
    float* __restrict__ blank_d,
    float* __restrict__ y_d,
    int B, int T, int U, int V) {
    const int wave = threadIdx.x >> 6;
    const int lane = threadIdx.x & 63;
    const long long row = (long long)blockIdx.x * 4 + wave;
    const long long nrows = (long long)B * T * (U + 1);
    if (row >= nrows) return;
    const float* base = logits + row * (long long)V;

    float4 d4[4];
    float vmax = -INFINITY;
#pragma unroll
    for (int c = 0; c < 4; ++c) {
        d4[c] = reinterpret_cast<const float4*>(base)[c * 64 + lane];
        vmax = fmaxf(vmax, fmaxf(fmaxf(d4[c].x, d4[c].y), fmaxf(d4[c].z, d4[c].w)));
    }
#pragma unroll
    for (int off = 32; off; off >>= 1) vmax = fmaxf(vmax, __shfl_xor(vmax, off, 64));
    float s = 0.f;
#pragma unroll
    for (int c = 0; c < 4; ++c) {
        s += __expf(d4[c].x - vmax) + __expf(d4[c].y - vmax) +
             __expf(d4[c].z - vmax) + __expf(d4[c].w - vmax);
    }
#pragma unroll
    for (int off = 32; off; off >>= 1) s += __shfl_xor(s, off, 64);

    if (lane == 0) {
        const float lse = vmax + __logf(s);
        const int U1 = U + 1;
        const int D = T + U;
        const int u = (int)(row % U1);
        const long long bt = row / U1;              // b*T + t
        const int b = (int)(bt / T);
        const int t = (int)(bt % T);
        blank_d[((long long)b * D + (t + u)) * U1 + u] = (base[0] - lse) * LOG2E;
        if (u < U) {
            const int tgt = targets[b * U + u];
            y_d[((long long)b * D + (t + u)) * U + u] = (base[tgt] - lse) * LOG2E;
        }
    }
}

// Stage 2: anti-diagonal wavefront, one wave per batch element, one block per
// CU. Lane l owns u=l; lane 63 also tracks u=64 (left neighbor is lane-local).
// Per diagonal: one DPP shift + one lae2 on the chain. 4-deep register
// prefetch ring (compile-time slot indices) hides L2 latency.
__global__ __launch_bounds__(64) void alpha_diag_kernel(
    const float* __restrict__ blank_d,
    const float* __restrict__ y_d,
    const int* __restrict__ in_len,
    const int* __restrict__ tgt_len,
    float* __restrict__ partials,
    int B, int T, int U) {
    const int b = blockIdx.x;
    const int lane = threadIdx.x & 63;
    const int D = T + U;
    const int P1 = U + 1;
    const int Dm1 = D - 1;

    const int Tb = in_len[b];
    const int L = tgt_len[b];
    const float* bd = blank_d + (long long)b * D * P1;
    const float* yd = y_d + (long long)b * D * U;
    const int dstar = Tb - 1 + L;

    float val = (lane == 0) ? 0.f : NEG;
    float v64 = NEG;
    const int ym = (lane > 0) ? (lane - 1) : 0;
    const bool t2ok = (lane >= 1) && (lane - 1 < L);
    const bool ok64 = (U - 1 < L);

    float bv[4], yv[4], b64[4], y63[4];
#pragma unroll
    for (int s = 0; s < 4; ++s) {
        int r = s; if (r > Dm1) r = Dm1;          // rows 0..3 for diags 1..4
        bv[s] = bd[r * P1 + lane];
        yv[s] = t2ok ? yd[r * U + ym] : NEG;      // mask at load (off-chain)
        b64[s] = bd[r * P1 + U];
        y63[s] = ok64 ? yd[r * U + (U - 1)] : NEG;
    }

    int d = 1;
    for (; d + 3 <= dstar; d += 4) {
#pragma unroll
        for (int s = 0; s < 4; ++s) {
            const int dd = d + s;
            const float pv = val;
            const float ps = shup1(pv);
            const float t1 = pv + bv[s];
            const float t2 = ps + yv[s];
            val = lae2(t1, t2);
            const float q1 = v64 + b64[s];
            const float q2 = pv + y63[s];
            v64 = lae2(q1, q2);
            int r = dd + 3; if (r > Dm1) r = Dm1; // row for diag dd+4
            bv[s] = bd[r * P1 + lane];
            yv[s] = t2ok ? yd[r * U + ym] : NEG;
            b64[s] = bd[r * P1 + U];
            y63[s] = ok64 ? yd[r * U + (U - 1)] : NEG;
        }
    }
    for (; d <= dstar; ++d) {                     // <=3 remainder iters, direct
        const int r = d - 1;
        const float bvx = bd[r * P1 + lane];
        const float yvx = t2ok ? yd[r * U + ym] : NEG;
        const float b64x = bd[r * P1 + U];
        const float y63x = ok64 ? yd[r * U + (U - 1)] : NEG;
        const float pv = val;
        const float ps = shup1(pv);
        val = lae2(pv + bvx, ps + yvx);
        v64 = lae2(v64 + b64x, pv + y63x);
    }

    const float aL = (L <= 63) ? __shfl(val, L, 64) : __shfl(v64, 63, 64);
    const float bfin = bd[(long long)dstar * P1 + L];
    if (lane == 0) partials[b] = aL + bfin;       // base-2 units
}

__global__ void finish_kernel(const float* __restrict__ partials,
                              float* __restrict__ out, int B) {
    if (threadIdx.x == 0) {
        float s = 0.f;
        for (int w = 0; w < B; ++w) s += partials[w];
        out[0] = -LN2 * s / (float)B;
    }
}

extern "C" void kernel_launch(void* const* d_in, const int* in_sizes, int n_in,
                              void* d_out, int out_size, void* d_ws, size_t ws_size,
                              hipStream_t stream) {
    const float* logits  = (const float*)d_in[0];
    const int* targets   = (const int*)d_in[1];
    const int* in_len    = (const int*)d_in[2];
    const int* tgt_len   = (const int*)d_in[3];

    const int B = in_sizes[2];
    const int U = in_sizes[1] / B;
    const int V = 1024;
    const int T = (int)((long long)in_sizes[0] / ((long long)B * (U + 1) * V));
    const int D = T + U;

    float* partials = (float*)d_ws;                       // 64 floats
    float* blank_d = partials + 64;
    float* y_d = blank_d + (long long)B * D * (U + 1);

    const long long rows = (long long)B * T * (U + 1);
    const int blocks = (int)((rows + 3) / 4);

    hipLaunchKernelGGL(lse_kernel, dim3(blocks), dim3(256), 0, stream,
                       logits, targets, blank_d, y_d, B, T, U, V);
    hipLaunchKernelGGL(alpha_diag_kernel, dim3(B), dim3(64), 0, stream,
                       blank_d, y_d, in_len, tgt_len, partials, B, T, U);
    hipLaunchKernelGGL(finish_kernel, dim3(1), dim3(64), 0, stream,
                       partials, (float*)d_out, B);
}